// Round 2
// baseline (929.114 us; speedup 1.0000x reference)
//
#include <hip/hip_runtime.h>
#include <hip/hip_cooperative_groups.h>

namespace cg = cooperative_groups;

// Problem constants (match reference setup_inputs)
#define BATCH 8
#define NPTS  18432
#define CH    1024
#define KOUT  1024
#define MAXS  18432   // segments per batch <= points per batch
#define CAP   64      // max points per selected voxel (Poisson lambda~0.7 -> unreachable)

#define GRID_BLOCKS   1024     // 4 blocks/CU on 256 CUs -> co-resident for cooperative launch
#define BLOCK_THREADS 256

// ---------------------------------------------------------------------------
// Single cooperative kernel, 4 phases separated by grid.sync():
//   P0: init map=-1, counts=0          (was hipMemsetAsync x2)
//   P1: scatter resample -> map        (was kernel A)
//   P2: point scan -> per-row lists    (was kernel B)
//   P3: wave-per-row gather-mean       (was kernel C, now 64-lane waves with
//       4x float4 per lane -> only 2 sequential rows per wave instead of 8
//       per block, deeper memory-level parallelism)
// Eliminates 4 kernel-boundary full drains + 2 memset launches.
// ---------------------------------------------------------------------------
__global__ __launch_bounds__(BLOCK_THREADS, 4)
void fused_pool_kernel(const float* __restrict__ feats,
                       const int*   __restrict__ p2v,
                       const int*   __restrict__ resample,
                       int*         __restrict__ map,
                       int*         __restrict__ counts,
                       int*         __restrict__ lists,
                       float*       __restrict__ out) {
    cg::grid_group grid = cg::this_grid();
    const int tid      = blockIdx.x * BLOCK_THREADS + threadIdx.x;  // 0..262143
    const int nthreads = GRID_BLOCKS * BLOCK_THREADS;               // 262144

    // ---- Phase 0: init ----
    for (int i = tid; i < BATCH * MAXS; i += nthreads) map[i] = -1;
    for (int i = tid; i < BATCH * KOUT; i += nthreads) counts[i] = 0;
    grid.sync();

    // ---- Phase 1: scatter resample indices into inverse map ----
    // (no duplicate resample indices at these sizes: choice(replace=False))
    for (int i = tid; i < BATCH * KOUT; i += nthreads) {
        int b = i >> 10;                       // KOUT = 1024
        map[b * MAXS + resample[i]] = i & (KOUT - 1);
    }
    grid.sync();

    // ---- Phase 2: build per-output-row point lists ----
    for (int i = tid; i < BATCH * NPTS; i += nthreads) {
        int b    = i / NPTS;
        int slot = map[b * MAXS + p2v[i]];     // -1 if voxel not selected (L2-hit)
        if (slot >= 0) {
            int row = (b << 10) + slot;
            int pos = atomicAdd(&counts[row], 1);
            if (pos < CAP) lists[row * CAP + pos] = i;
        }
    }
    grid.sync();

    // ---- Phase 3: gather + mean, one 64-lane wave per output row ----
    const int wid    = tid >> 6;               // 0..4095
    const int lane   = tid & 63;
    const int nwaves = nthreads >> 6;          // 4096 -> 2 rows per wave
    for (int row = wid; row < BATCH * KOUT; row += nwaves) {
        int cnt = counts[row];
        int n   = cnt < CAP ? cnt : CAP;
        float4 a0 = make_float4(0.f, 0.f, 0.f, 0.f);
        float4 a1 = make_float4(0.f, 0.f, 0.f, 0.f);
        float4 a2 = make_float4(0.f, 0.f, 0.f, 0.f);
        float4 a3 = make_float4(0.f, 0.f, 0.f, 0.f);
        for (int j = 0; j < n; ++j) {
            int pt = lists[row * CAP + j];     // wave-uniform
            const float4* src = (const float4*)(feats + (size_t)pt * CH);
            float4 v0 = src[lane];
            float4 v1 = src[lane + 64];
            float4 v2 = src[lane + 128];
            float4 v3 = src[lane + 192];
            a0.x += v0.x; a0.y += v0.y; a0.z += v0.z; a0.w += v0.w;
            a1.x += v1.x; a1.y += v1.y; a1.z += v1.z; a1.w += v1.w;
            a2.x += v2.x; a2.y += v2.y; a2.z += v2.z; a2.w += v2.w;
            a3.x += v3.x; a3.y += v3.y; a3.z += v3.z; a3.w += v3.w;
        }
        float inv = 1.0f / (float)(cnt > 0 ? cnt : 1);
        a0.x *= inv; a0.y *= inv; a0.z *= inv; a0.w *= inv;
        a1.x *= inv; a1.y *= inv; a1.z *= inv; a1.w *= inv;
        a2.x *= inv; a2.y *= inv; a2.z *= inv; a2.w *= inv;
        a3.x *= inv; a3.y *= inv; a3.z *= inv; a3.w *= inv;
        float4* dst = (float4*)(out + (size_t)row * CH);
        dst[lane]       = a0;
        dst[lane + 64]  = a1;
        dst[lane + 128] = a2;
        dst[lane + 192] = a3;
    }
}

extern "C" void kernel_launch(void* const* d_in, const int* in_sizes, int n_in,
                              void* d_out, int out_size, void* d_ws, size_t ws_size,
                              hipStream_t stream) {
    const float* feats    = (const float*)d_in[0];  // [B,N,C] f32
    const int*   p2v      = (const int*)  d_in[1];  // [B,N]   i32
    const int*   resample = (const int*)  d_in[2];  // [B,K]   i32
    // d_in[3] = num_segments (scalar) — MAXS=N is a safe upper bound.
    float* out = (float*)d_out;                     // [B,K,C] f32

    int* map    = (int*)d_ws;                       // [B, MAXS]      590 KB
    int* counts = map + BATCH * MAXS;               // [B, K]          32 KB
    int* lists  = counts + BATCH * KOUT;            // [B*K, CAP]       2 MB

    void* args[] = {
        (void*)&feats, (void*)&p2v, (void*)&resample,
        (void*)&map, (void*)&counts, (void*)&lists, (void*)&out
    };
    hipLaunchCooperativeKernel((const void*)fused_pool_kernel,
                               dim3(GRID_BLOCKS), dim3(BLOCK_THREADS),
                               args, 0, stream);
}

// Round 3
// 667.126 us; speedup vs baseline: 1.3927x; 1.3927x over previous
//
#include <hip/hip_runtime.h>

// Problem constants (match reference setup_inputs)
#define BATCH 8
#define NPTS  18432
#define CH    1024
#define KOUT  1024
#define MAXS  18432   // segments per batch <= points per batch
#define CAP   64      // max points per selected voxel (Poisson lambda~0.7 -> unreachable)

// ---------------------------------------------------------------------------
// Kernel 0: init map=-1 and counts=0 in one dispatch (replaces 2 memset nodes).
// 155648 words total -> one grid-stride pass, trivial duration.
// ---------------------------------------------------------------------------
__global__ void init_kernel(int* __restrict__ map, int* __restrict__ counts) {
    int i = blockIdx.x * blockDim.x + threadIdx.x;
    int stride = gridDim.x * blockDim.x;
    for (int j = i; j < BATCH * MAXS; j += stride) map[j] = -1;
    for (int j = i; j < BATCH * KOUT; j += stride) counts[j] = 0;
}

// ---------------------------------------------------------------------------
// Kernel A: scatter resample indices into the inverse map.
// map[b*MAXS + vox] = k. Duplicate resample indices (only possible if a batch
// had < K voxels, which doesn't happen at these sizes) would just make the
// duplicated rows recompute the same mean independently — still correct.
// ---------------------------------------------------------------------------
__global__ void scatter_map_kernel(const int* __restrict__ resample,
                                   int* __restrict__ map) {
    int i = blockIdx.x * blockDim.x + threadIdx.x;   // 0 .. B*K-1
    if (i >= BATCH * KOUT) return;
    int b = i / KOUT;
    int vox = resample[i];
    map[b * MAXS + vox] = i - b * KOUT;              // k
}

// ---------------------------------------------------------------------------
// Kernel B: one thread per point. If the point's voxel was resampled, append
// the point's global row index to that output slot's list (atomic cursor).
// Only ~7.7% of points survive the map test; p2v/map reads are tiny (L2).
// ---------------------------------------------------------------------------
__global__ void build_lists_kernel(const int* __restrict__ p2v,
                                   const int* __restrict__ map,
                                   int* __restrict__ counts,
                                   int* __restrict__ lists) {
    int i = blockIdx.x * blockDim.x + threadIdx.x;   // global point id, 0..B*N-1
    if (i >= BATCH * NPTS) return;
    int b = i / NPTS;
    int vox = p2v[i];
    int slot = map[b * MAXS + vox];                  // -1 if voxel not selected
    if (slot < 0) return;
    int row = b * KOUT + slot;
    int pos = atomicAdd(&counts[row], 1);
    if (pos < CAP) lists[row * CAP + pos] = i;
}

// ---------------------------------------------------------------------------
// Kernel C: one 256-thread block per output row (b,k). Gather the listed
// point rows (avg ~1.4), accumulate in registers (float4/thread), divide by
// the true count, write the output row exactly once. No atomics, no second
// pass, no zero-init of d_out. (Verified shape from the 669 µs baseline.)
// ---------------------------------------------------------------------------
__global__ void gather_mean_kernel(const float* __restrict__ feats,
                                   const int* __restrict__ counts,
                                   const int* __restrict__ lists,
                                   float* __restrict__ out) {
    int row = blockIdx.x;                            // b*KOUT + k
    int cnt = counts[row];
    int n = cnt < CAP ? cnt : CAP;
    float4 acc = make_float4(0.f, 0.f, 0.f, 0.f);
    for (int j = 0; j < n; ++j) {
        int pt = lists[row * CAP + j];               // wave-uniform, L2-hit
        float4 v = ((const float4*)(feats + (size_t)pt * CH))[threadIdx.x];
        acc.x += v.x; acc.y += v.y; acc.z += v.z; acc.w += v.w;
    }
    float inv = 1.0f / (float)(cnt > 0 ? cnt : 1);
    acc.x *= inv; acc.y *= inv; acc.z *= inv; acc.w *= inv;
    ((float4*)(out + (size_t)row * CH))[threadIdx.x] = acc;
}

extern "C" void kernel_launch(void* const* d_in, const int* in_sizes, int n_in,
                              void* d_out, int out_size, void* d_ws, size_t ws_size,
                              hipStream_t stream) {
    const float* feats    = (const float*)d_in[0];  // [B,N,C] f32
    const int*   p2v      = (const int*)  d_in[1];  // [B,N]   i32
    const int*   resample = (const int*)  d_in[2];  // [B,K]   i32
    // d_in[3] = num_segments (scalar) — MAXS=N is a safe upper bound.
    float* out = (float*)d_out;                     // [B,K,C] f32

    int* map    = (int*)d_ws;                       // [B, MAXS]      590 KB
    int* counts = map + BATCH * MAXS;               // [B, K]          32 KB
    int* lists  = counts + BATCH * KOUT;            // [B*K, CAP]       2 MB

    init_kernel<<<256, 256, 0, stream>>>(map, counts);

    scatter_map_kernel<<<(BATCH * KOUT + 255) / 256, 256, 0, stream>>>(resample, map);

    build_lists_kernel<<<(BATCH * NPTS + 255) / 256, 256, 0, stream>>>(
        p2v, map, counts, lists);

    gather_mean_kernel<<<BATCH * KOUT, 256, 0, stream>>>(feats, counts, lists, out);
}

// Round 4
// 664.586 us; speedup vs baseline: 1.3980x; 1.0038x over previous
//
#include <hip/hip_runtime.h>

// Problem constants (match reference setup_inputs)
#define BATCH 8
#define NPTS  18432
#define CH    1024
#define KOUT  1024
#define MAXS  18432   // segments per batch <= points per batch
#define CAP   64      // max points per selected voxel (Poisson lambda~0.7 -> unreachable)

// ---------------------------------------------------------------------------
// Kernel A: scatter resample indices into the (UNINITIALIZED) inverse map,
// and zero the per-row counts in the same dispatch (disjoint writes).
//
// map needs no init: build_lists back-validates every entry with
// resample[b, slot] == vox, which stale/poison data cannot satisfy for a
// non-selected voxel (resample[b,g] is always a selected voxel). Exact, not
// probabilistic. Saves the init dispatch + its drain.
// ---------------------------------------------------------------------------
__global__ void scatter_map_kernel(const int* __restrict__ resample,
                                   int* __restrict__ map,
                                   int* __restrict__ counts) {
    int i = blockIdx.x * blockDim.x + threadIdx.x;   // 0 .. B*K-1
    if (i >= BATCH * KOUT) return;
    counts[i] = 0;
    int b = i >> 10;                                 // KOUT = 1024
    int vox = resample[i];
    map[b * MAXS + vox] = i & (KOUT - 1);            // k
}

// ---------------------------------------------------------------------------
// Kernel B: one thread per point. slot = map[vox] is trusted only after the
// back-check resample[b,slot]==vox (see above). Valid points append their
// global row index to the output slot's list (atomic cursor).
// Only ~7.7% of points survive; p2v read is coalesced, map/resample reads
// are small (<1 MB total, L2).
// ---------------------------------------------------------------------------
__global__ void build_lists_kernel(const int* __restrict__ p2v,
                                   const int* __restrict__ map,
                                   const int* __restrict__ resample,
                                   int* __restrict__ counts,
                                   int* __restrict__ lists) {
    int i = blockIdx.x * blockDim.x + threadIdx.x;   // global point id, 0..B*N-1
    if (i >= BATCH * NPTS) return;
    int b = i / NPTS;
    int vox = p2v[i];
    int slot = map[b * MAXS + vox];                  // possibly stale garbage
    if (slot < 0 || slot >= KOUT) return;            // range-guard OOB garbage
    if (resample[(b << 10) + slot] != vox) return;   // back-check: exact filter
    int row = (b << 10) + slot;
    int pos = atomicAdd(&counts[row], 1);
    if (pos < CAP) lists[row * CAP + pos] = i;
}

// ---------------------------------------------------------------------------
// Kernel C: one 256-thread block per output row (b,k). Gather the listed
// point rows (avg ~1.4), accumulate in registers (float4/thread), divide by
// the true count, write the output row exactly once. No atomics, no second
// pass, no zero-init of d_out. (Verified shape from the 667-669 µs baseline.)
// ---------------------------------------------------------------------------
__global__ void gather_mean_kernel(const float* __restrict__ feats,
                                   const int* __restrict__ counts,
                                   const int* __restrict__ lists,
                                   float* __restrict__ out) {
    int row = blockIdx.x;                            // b*KOUT + k
    int cnt = counts[row];
    int n = cnt < CAP ? cnt : CAP;
    float4 acc = make_float4(0.f, 0.f, 0.f, 0.f);
    for (int j = 0; j < n; ++j) {
        int pt = lists[row * CAP + j];               // wave-uniform, L2-hit
        float4 v = ((const float4*)(feats + (size_t)pt * CH))[threadIdx.x];
        acc.x += v.x; acc.y += v.y; acc.z += v.z; acc.w += v.w;
    }
    float inv = 1.0f / (float)(cnt > 0 ? cnt : 1);
    acc.x *= inv; acc.y *= inv; acc.z *= inv; acc.w *= inv;
    ((float4*)(out + (size_t)row * CH))[threadIdx.x] = acc;
}

extern "C" void kernel_launch(void* const* d_in, const int* in_sizes, int n_in,
                              void* d_out, int out_size, void* d_ws, size_t ws_size,
                              hipStream_t stream) {
    const float* feats    = (const float*)d_in[0];  // [B,N,C] f32
    const int*   p2v      = (const int*)  d_in[1];  // [B,N]   i32
    const int*   resample = (const int*)  d_in[2];  // [B,K]   i32
    // d_in[3] = num_segments (scalar) — MAXS=N is a safe upper bound.
    float* out = (float*)d_out;                     // [B,K,C] f32

    int* map    = (int*)d_ws;                       // [B, MAXS]      590 KB (uninit OK)
    int* counts = map + BATCH * MAXS;               // [B, K]          32 KB
    int* lists  = counts + BATCH * KOUT;            // [B*K, CAP]       2 MB

    scatter_map_kernel<<<(BATCH * KOUT + 255) / 256, 256, 0, stream>>>(
        resample, map, counts);

    build_lists_kernel<<<(BATCH * NPTS + 255) / 256, 256, 0, stream>>>(
        p2v, map, resample, counts, lists);

    gather_mean_kernel<<<BATCH * KOUT, 256, 0, stream>>>(feats, counts, lists, out);
}